// Round 6
// baseline (86.838 us; speedup 1.0000x reference)
//
#include <hip/hip_runtime.h>
#include <math.h>

#define BB 16
#define TT 2048
#define DD 1024
#define HH 64
#define QK_SCALE 0.18033688011112042f  // 0.125 * log2(e)  (exp2-domain softmax)

typedef short bf16x8 __attribute__((ext_vector_type(8)));
typedef short bf16x4 __attribute__((ext_vector_type(4)));
typedef float f32x4 __attribute__((ext_vector_type(4)));

__device__ __forceinline__ short f2bf(float f) {  // RNE
  union { float f; unsigned u; } c; c.f = f;
  unsigned u = c.u + 0x7FFFu + ((c.u >> 16) & 1u);
  return (short)(u >> 16);
}
__device__ __forceinline__ short f2bf_up(float f) {  // round-half-up (P>=0)
  union { float f; unsigned u; } c; c.f = f;
  return (short)((c.u + 0x8000u) >> 16);
}

// 64-col bf16 tile (128B row stride): XOR-swizzle 16B units by row&7.
__device__ __forceinline__ void* lds_swz(void* base, int row, int col) {
  int byte = (row << 7) + (col << 1);
  byte ^= (row & 7) << 4;
  return (void*)((char*)base + byte);
}
// 128-col bf16 tile (256B row stride).
__device__ __forceinline__ void* lds_swz256(void* base, int row, int col) {
  int byte = (row << 8) + (col << 1);
  byte ^= (row & 7) << 4;
  return (void*)((char*)base + byte);
}

__device__ __forceinline__ void pack16(const float4& a0, const float4& a1,
                                       const float4& a2, const float4& a3,
                                       bf16x8& s0, bf16x8& s1) {
  s0[0] = f2bf(a0.x); s0[1] = f2bf(a0.y); s0[2] = f2bf(a0.z); s0[3] = f2bf(a0.w);
  s0[4] = f2bf(a1.x); s0[5] = f2bf(a1.y); s0[6] = f2bf(a1.z); s0[7] = f2bf(a1.w);
  s1[0] = f2bf(a2.x); s1[1] = f2bf(a2.y); s1[2] = f2bf(a2.z); s1[3] = f2bf(a2.w);
  s1[4] = f2bf(a3.x); s1[5] = f2bf(a3.y); s1[6] = f2bf(a3.z); s1[7] = f2bf(a3.w);
}

// ---------------------------------------------------------------------------
// Pack Wq|Wk|Wv (fp32 [D][H]) -> Wt bf16 [192][1024]  (n-major, k contiguous)
// ---------------------------------------------------------------------------
__global__ __launch_bounds__(256) void pack_wt(
    const float* __restrict__ Wq, const float* __restrict__ Wk,
    const float* __restrict__ Wv, short* __restrict__ wt) {
  const int idx = blockIdx.x * 256 + threadIdx.x;
  const int n = idx >> 7;
  const int k0 = (idx & 127) << 3;
  const float* W = (n < 64) ? Wq : (n < 128) ? Wk : Wv;
  const int h = n & 63;
  bf16x8 o;
#pragma unroll
  for (int j = 0; j < 8; ++j) o[j] = f2bf(W[(k0 + j) * HH + h]);
  *(bf16x8*)&wt[n * DD + k0] = o;
}

// ---------------------------------------------------------------------------
// QKV GEMM, double-buffered bf16 MFMA. Q output pre-scaled by QK_SCALE.
// V written transposed to vt [b][h][t].
// ---------------------------------------------------------------------------
__global__ __launch_bounds__(256) void qkv_mfma(
    const float* __restrict__ x, const short* __restrict__ wt,
    short* __restrict__ qo, short* __restrict__ ko, short* __restrict__ vt) {
  __shared__ short xs[2][64 * 64];
  const int tid = threadIdx.x;
  const int lane = tid & 63;
  const int w = tid >> 6;
  const int q16 = lane & 15;
  const int g = lane >> 4;
  const size_t r0 = (size_t)blockIdx.x * 64;

  const int srow = tid >> 2;
  const int sc = (tid & 3) << 4;
  const float* xrow = x + (r0 + srow) * DD + sc;

  f32x4 acc[4][3];
#pragma unroll
  for (int mf = 0; mf < 4; ++mf)
#pragma unroll
    for (int nf = 0; nf < 3; ++nf) acc[mf][nf] = (f32x4){0.f, 0.f, 0.f, 0.f};

  const short* wp[3];
#pragma unroll
  for (int nf = 0; nf < 3; ++nf)
    wp[nf] = wt + (size_t)(w * 48 + nf * 16 + q16) * DD + g * 8;

  {
    const float4* xp = (const float4*)xrow;
    float4 a0 = xp[0], a1 = xp[1], a2 = xp[2], a3 = xp[3];
    bf16x8 s0, s1;
    pack16(a0, a1, a2, a3, s0, s1);
    *(bf16x8*)lds_swz(xs[0], srow, sc) = s0;
    *(bf16x8*)lds_swz(xs[0], srow, sc + 8) = s1;
  }
  bf16x8 bcur[3][2];
#pragma unroll
  for (int nf = 0; nf < 3; ++nf)
#pragma unroll
    for (int kf = 0; kf < 2; ++kf)
      bcur[nf][kf] = *(const bf16x8*)(wp[nf] + kf * 32);
  __syncthreads();

  int cur = 0;
  for (int ks = 0; ks < 16; ++ks) {
    float4 a0, a1, a2, a3;
    bf16x8 bnxt[3][2];
    if (ks < 15) {
      const int k1 = (ks + 1) << 6;
      const float4* xp = (const float4*)(xrow + k1);
      a0 = xp[0]; a1 = xp[1]; a2 = xp[2]; a3 = xp[3];
#pragma unroll
      for (int nf = 0; nf < 3; ++nf)
#pragma unroll
        for (int kf = 0; kf < 2; ++kf)
          bnxt[nf][kf] = *(const bf16x8*)(wp[nf] + k1 + kf * 32);
    }

    bf16x8 afr[4][2];
#pragma unroll
    for (int mf = 0; mf < 4; ++mf)
#pragma unroll
      for (int kf = 0; kf < 2; ++kf)
        afr[mf][kf] = *(bf16x8*)lds_swz(xs[cur], mf * 16 + q16, kf * 32 + g * 8);

#pragma unroll
    for (int mf = 0; mf < 4; ++mf)
#pragma unroll
      for (int nf = 0; nf < 3; ++nf)
#pragma unroll
        for (int kf = 0; kf < 2; ++kf)
          acc[mf][nf] = __builtin_amdgcn_mfma_f32_16x16x32_bf16(
              afr[mf][kf], bcur[nf][kf], acc[mf][nf], 0, 0, 0);

    if (ks < 15) {
      bf16x8 s0, s1;
      pack16(a0, a1, a2, a3, s0, s1);
      *(bf16x8*)lds_swz(xs[cur ^ 1], srow, sc) = s0;
      *(bf16x8*)lds_swz(xs[cur ^ 1], srow, sc + 8) = s1;
      __syncthreads();
      cur ^= 1;
#pragma unroll
      for (int nf = 0; nf < 3; ++nf)
#pragma unroll
        for (int kf = 0; kf < 2; ++kf) bcur[nf][kf] = bnxt[nf][kf];
    }
  }

#pragma unroll
  for (int nf = 0; nf < 3; ++nf) {
    const int n = w * 48 + nf * 16 + q16;
    const int mat = n >> 6;  // frag-uniform
    const int h = n & 63;
    if (mat < 2) {
      short* outp = mat ? ko : qo;
      const float fac = mat ? 1.0f : QK_SCALE;
#pragma unroll
      for (int mf = 0; mf < 4; ++mf)
#pragma unroll
        for (int r = 0; r < 4; ++r)
          outp[(r0 + mf * 16 + g * 4 + r) * HH + h] = f2bf(acc[mf][nf][r] * fac);
    } else {
      const int bb = (int)(r0 >> 11);
      const int tloc = (int)(r0 & 2047);
#pragma unroll
      for (int mf = 0; mf < 4; ++mf) {
        bf16x4 pk;
#pragma unroll
        for (int r = 0; r < 4; ++r) pk[r] = f2bf(acc[mf][nf][r]);
        *(bf16x4*)&vt[((size_t)bb * HH + h) * TT + tloc + mf * 16 + g * 4] = pk;
      }
    }
  }
}

// ---------------------------------------------------------------------------
// Flash attention, bf16 MFMA. 256 thr = 4 waves, one 64-row q-tile/block.
// Grid (32,16), complementary-tile swizzle: qt = (by>=8) ? bx : 31-bx so
// co-resident blocks n and n+256 carry NC(u)+NC(31-u)=17 chunks (flat CU
// load). KVBLK=128, single-buffer LDS (49 KB -> 3 blocks/CU) with T14
// reg-held prefetch; exp2-domain softmax, defer-max, l via ones-MFMA.
// ---------------------------------------------------------------------------
__global__ __launch_bounds__(256, 3) void attn_mfma(
    const short* __restrict__ q, const short* __restrict__ k,
    const short* __restrict__ vt, float* __restrict__ out) {
  __shared__ short klds[128 * 64];   // 16 KB, K [key][d]
  __shared__ short vlds[64 * 128];   // 16 KB, V^T [h][key] (also Q scratch)
  __shared__ short ps[4][16 * 136];  // 17 KB, per-wave P [16q][136]

  const int bx = blockIdx.x;  // 0..31
  const int b = blockIdx.y;   // 0..15
  const int qt = (b >= 8) ? bx : (31 - bx);
  const int t0 = qt << 6;
  const int tid = threadIdx.x;
  const int lane = tid & 63;
  const int w = tid >> 6;     // 0..3
  const int q16 = lane & 15;
  const int g = lane >> 4;
  const int NC = (qt >> 1) + 1;          // 128-key chunks
  const int qrow = t0 + w * 16 + g * 4;  // + r

  const size_t brow = (size_t)b * TT;
  const short* kg = k + brow * HH;
  const short* vtg = vt + (size_t)b * HH * TT;

  const int krow = tid >> 1;        // 0..127
  const int kcol = (tid & 1) << 5;  // 0,32
  const int vrow = tid >> 2;        // 0..63
  const int vcol = (tid & 3) << 5;  // 0,32,64,96

  // issue chunk-0 K/V loads first
  bf16x8 kr[4], vr[4];
#pragma unroll
  for (int j = 0; j < 4; ++j) {
    kr[j] = *(const bf16x8*)&kg[krow * HH + kcol + j * 8];
    vr[j] = *(const bf16x8*)&vtg[vrow * TT + vcol + j * 8];
  }

  // stage Q via vlds scratch, pull per-wave A-frags
  {
    const int qsr = tid >> 2;
    const int qsc = (tid & 3) << 4;
    const short* qsrc = q + (brow + t0 + qsr) * HH;
    *(bf16x8*)lds_swz(vlds, qsr, qsc) = *(const bf16x8*)&qsrc[qsc];
    *(bf16x8*)lds_swz(vlds, qsr, qsc + 8) = *(const bf16x8*)&qsrc[qsc + 8];
  }
  __syncthreads();
  bf16x8 qa[2];
#pragma unroll
  for (int kf = 0; kf < 2; ++kf)
    qa[kf] = *(bf16x8*)lds_swz(vlds, w * 16 + q16, kf * 32 + g * 8);
  __syncthreads();

  // write chunk 0
#pragma unroll
  for (int j = 0; j < 4; ++j) {
    *(bf16x8*)lds_swz(klds, krow, kcol + j * 8) = kr[j];
    *(bf16x8*)lds_swz256(vlds, vrow, vcol + j * 8) = vr[j];
  }
  __syncthreads();

  f32x4 po[4];
  f32x4 lacc = (f32x4){0.f, 0.f, 0.f, 0.f};
  float m[4];
#pragma unroll
  for (int nf = 0; nf < 4; ++nf) po[nf] = (f32x4){0.f, 0.f, 0.f, 0.f};
#pragma unroll
  for (int r = 0; r < 4; ++r) m[r] = -INFINITY;

  const bf16x8 ones = {0x3F80, 0x3F80, 0x3F80, 0x3F80,
                       0x3F80, 0x3F80, 0x3F80, 0x3F80};

  for (int c = 0; c < NC; ++c) {
    const bool notlast = (c + 1 < NC);
    if (notlast) {  // T14: issue next chunk's globals before compute
      const int s1 = (c + 1) << 7;
#pragma unroll
      for (int j = 0; j < 4; ++j) {
        kr[j] = *(const bf16x8*)&kg[(s1 + krow) * HH + kcol + j * 8];
        vr[j] = *(const bf16x8*)&vtg[vrow * TT + s1 + vcol + j * 8];
      }
    }

    // ---- S = Q . K^T (exp2-domain: Q pre-scaled) ----
    f32x4 sfr[8];
#pragma unroll
    for (int nf = 0; nf < 8; ++nf) sfr[nf] = (f32x4){0.f, 0.f, 0.f, 0.f};
    __builtin_amdgcn_s_setprio(1);
#pragma unroll
    for (int nf = 0; nf < 8; ++nf)
#pragma unroll
      for (int kf = 0; kf < 2; ++kf) {
        bf16x8 kb = *(bf16x8*)lds_swz(klds, nf * 16 + q16, kf * 32 + g * 8);
        sfr[nf] = __builtin_amdgcn_mfma_f32_16x16x32_bf16(qa[kf], kb, sfr[nf], 0, 0, 0);
      }
    __builtin_amdgcn_s_setprio(0);

    // ---- causal mask: diagonal (last) chunk only ----
    if (c == NC - 1) {
      const int sbase = (c << 7) + q16;
#pragma unroll
      for (int nf = 0; nf < 8; ++nf)
#pragma unroll
        for (int r = 0; r < 4; ++r)
          if (sbase + nf * 16 > qrow + r) sfr[nf][r] = -INFINITY;
    }

    // ---- row max ----
    float pm[4];
#pragma unroll
    for (int r = 0; r < 4; ++r) {
      float a = fmaxf(fmaxf(sfr[0][r], sfr[1][r]), fmaxf(sfr[2][r], sfr[3][r]));
      float bx2 = fmaxf(fmaxf(sfr[4][r], sfr[5][r]), fmaxf(sfr[6][r], sfr[7][r]));
      pm[r] = fmaxf(a, bx2);
    }
#pragma unroll
    for (int off = 8; off; off >>= 1)
#pragma unroll
      for (int r = 0; r < 4; ++r) pm[r] = fmaxf(pm[r], __shfl_xor(pm[r], off));

    // ---- defer-max (T13, THR=8 log2 units) ----
    float growth = fmaxf(fmaxf(pm[0] - m[0], pm[1] - m[1]),
                         fmaxf(pm[2] - m[2], pm[3] - m[3]));
    if (__any(growth > 8.f)) {
#pragma unroll
      for (int r = 0; r < 4; ++r) {
        const float mn = fmaxf(m[r], pm[r]);
        const float corr = exp2f(m[r] - mn);
        m[r] = mn;
        lacc[r] *= corr;
#pragma unroll
        for (int nf = 0; nf < 4; ++nf) po[nf][r] *= corr;
      }
    }

    // ---- P = exp2(S - m) -> bf16 -> per-wave LDS [16q][136] ----
#pragma unroll
    for (int nf = 0; nf < 8; ++nf)
#pragma unroll
      for (int r = 0; r < 4; ++r)
        ps[w][(g * 4 + r) * 136 + nf * 16 + q16] = f2bf_up(exp2f(sfr[nf][r] - m[r]));

    // ---- O += P.V ; l += P.1 ----
    bf16x8 pa[4];
#pragma unroll
    for (int kf = 0; kf < 4; ++kf)
      pa[kf] = *(const bf16x8*)&ps[w][q16 * 136 + kf * 32 + g * 8];
    __builtin_amdgcn_s_setprio(1);
#pragma unroll
    for (int nf = 0; nf < 4; ++nf)
#pragma unroll
      for (int kf = 0; kf < 4; ++kf) {
        bf16x8 vb = *(bf16x8*)lds_swz256(vlds, nf * 16 + q16, kf * 32 + g * 8);
        po[nf] = __builtin_amdgcn_mfma_f32_16x16x32_bf16(pa[kf], vb, po[nf], 0, 0, 0);
      }
#pragma unroll
    for (int kf = 0; kf < 4; ++kf)
      lacc = __builtin_amdgcn_mfma_f32_16x16x32_bf16(pa[kf], ones, lacc, 0, 0, 0);
    __builtin_amdgcn_s_setprio(0);

    if (notlast) {
      __syncthreads();  // all waves done reading chunk c
#pragma unroll
      for (int j = 0; j < 4; ++j) {
        *(bf16x8*)lds_swz(klds, krow, kcol + j * 8) = kr[j];
        *(bf16x8*)lds_swz256(vlds, vrow, vcol + j * 8) = vr[j];
      }
      __syncthreads();  // staging visible
    }
  }

#pragma unroll
  for (int nf = 0; nf < 4; ++nf) {
    const int h = nf * 16 + q16;
#pragma unroll
    for (int r = 0; r < 4; ++r)
      out[(brow + qrow + r) * HH + h] = po[nf][r] / lacc[r];
  }
}

extern "C" void kernel_launch(void* const* d_in, const int* in_sizes, int n_in,
                              void* d_out, int out_size, void* d_ws, size_t ws_size,
                              hipStream_t stream) {
  const float* x  = (const float*)d_in[0];
  const float* Wq = (const float*)d_in[1];
  const float* Wk = (const float*)d_in[2];
  const float* Wv = (const float*)d_in[3];
  float* out = (float*)d_out;

  const size_t bth = (size_t)BB * TT * HH;  // 2,097,152
  short* qb  = (short*)d_ws;
  short* kb  = qb + bth;
  short* vtb = kb + bth;
  short* wtb = vtb + bth;  // 192*1024 bf16

  pack_wt<<<96, 256, 0, stream>>>(Wq, Wk, Wv, wtb);
  qkv_mfma<<<(BB * TT) / 64, 256, 0, stream>>>(x, wtb, qb, kb, vtb);
  attn_mfma<<<dim3(32, BB), 256, 0, stream>>>(qb, kb, vtb, out);
}

// Round 8
// 80.645 us; speedup vs baseline: 1.0768x; 1.0768x over previous
//
#include <hip/hip_runtime.h>
#include <math.h>

#define BB 16
#define TT 2048
#define DD 1024
#define HH 64
#define QK_SCALE 0.18033688011112042f  // 0.125 * log2(e)  (exp2-domain softmax)

typedef short bf16x8 __attribute__((ext_vector_type(8)));
typedef short bf16x4 __attribute__((ext_vector_type(4)));
typedef float f32x4 __attribute__((ext_vector_type(4)));

__device__ __forceinline__ short f2bf(float f) {  // RNE
  union { float f; unsigned u; } c; c.f = f;
  unsigned u = c.u + 0x7FFFu + ((c.u >> 16) & 1u);
  return (short)(u >> 16);
}
__device__ __forceinline__ short f2bf_up(float f) {  // round-half-up (P>=0)
  union { float f; unsigned u; } c; c.f = f;
  return (short)((c.u + 0x8000u) >> 16);
}

// 64-col bf16 tile (128B row stride): XOR-swizzle 16B units by row&7.
__device__ __forceinline__ void* lds_swz(void* base, int row, int col) {
  int byte = (row << 7) + (col << 1);
  byte ^= (row & 7) << 4;
  return (void*)((char*)base + byte);
}

__device__ __forceinline__ void pack16(const float4& a0, const float4& a1,
                                       const float4& a2, const float4& a3,
                                       bf16x8& s0, bf16x8& s1) {
  s0[0] = f2bf(a0.x); s0[1] = f2bf(a0.y); s0[2] = f2bf(a0.z); s0[3] = f2bf(a0.w);
  s0[4] = f2bf(a1.x); s0[5] = f2bf(a1.y); s0[6] = f2bf(a1.z); s0[7] = f2bf(a1.w);
  s1[0] = f2bf(a2.x); s1[1] = f2bf(a2.y); s1[2] = f2bf(a2.z); s1[3] = f2bf(a2.w);
  s1[4] = f2bf(a3.x); s1[5] = f2bf(a3.y); s1[6] = f2bf(a3.z); s1[7] = f2bf(a3.w);
}

// ---------------------------------------------------------------------------
// Pack Wq|Wk|Wv (fp32 [D][H]) -> Wt bf16 [192][1024]  (n-major, k contiguous)
// ---------------------------------------------------------------------------
__global__ __launch_bounds__(256) void pack_wt(
    const float* __restrict__ Wq, const float* __restrict__ Wk,
    const float* __restrict__ Wv, short* __restrict__ wt) {
  const int idx = blockIdx.x * 256 + threadIdx.x;
  const int n = idx >> 7;
  const int k0 = (idx & 127) << 3;
  const float* W = (n < 64) ? Wq : (n < 128) ? Wk : Wv;
  const int h = n & 63;
  bf16x8 o;
#pragma unroll
  for (int j = 0; j < 8; ++j) o[j] = f2bf(W[(k0 + j) * HH + h]);
  *(bf16x8*)&wt[n * DD + k0] = o;
}

// ---------------------------------------------------------------------------
// QKV GEMM, bf16 MFMA, depth-2 x prefetch. Q pre-scaled by QK_SCALE;
// V written transposed to vt [b][h][t].
// ---------------------------------------------------------------------------
__global__ __launch_bounds__(256) void qkv_mfma(
    const float* __restrict__ x, const short* __restrict__ wt,
    short* __restrict__ qo, short* __restrict__ ko, short* __restrict__ vt) {
  __shared__ short xs[2][64 * 64];
  const int tid = threadIdx.x;
  const int lane = tid & 63;
  const int w = tid >> 6;
  const int q16 = lane & 15;
  const int g = lane >> 4;
  const size_t r0 = (size_t)blockIdx.x * 64;

  const int srow = tid >> 2;
  const int sc = (tid & 3) << 4;
  const float* xrow = x + (r0 + srow) * DD + sc;

  f32x4 acc[4][3];
#pragma unroll
  for (int mf = 0; mf < 4; ++mf)
#pragma unroll
    for (int nf = 0; nf < 3; ++nf) acc[mf][nf] = (f32x4){0.f, 0.f, 0.f, 0.f};

  const short* wp[3];
#pragma unroll
  for (int nf = 0; nf < 3; ++nf)
    wp[nf] = wt + (size_t)(w * 48 + nf * 16 + q16) * DD + g * 8;

  float4 xa[2][4];  // two in-flight x reg-sets (unroll-2 keeps idx static)
  {
    const float4* xp = (const float4*)xrow;
#pragma unroll
    for (int j = 0; j < 4; ++j) xa[0][j] = xp[j];
    bf16x8 s0, s1;
    pack16(xa[0][0], xa[0][1], xa[0][2], xa[0][3], s0, s1);
    *(bf16x8*)lds_swz(xs[0], srow, sc) = s0;
    *(bf16x8*)lds_swz(xs[0], srow, sc + 8) = s1;
    const float4* xp1 = (const float4*)(xrow + 64);
#pragma unroll
    for (int j = 0; j < 4; ++j) xa[1][j] = xp1[j];
  }
  bf16x8 bcur[3][2];
#pragma unroll
  for (int nf = 0; nf < 3; ++nf)
#pragma unroll
    for (int kf = 0; kf < 2; ++kf)
      bcur[nf][kf] = *(const bf16x8*)(wp[nf] + kf * 32);
  __syncthreads();

  int cur = 0;
#pragma unroll 2
  for (int ks = 0; ks < 16; ++ks) {
    const int pnext = (ks + 1) & 1;  // set holding x(ks+1)
    const int pfree = ks & 1;        // set to refill with x(ks+2)
    if (ks < 14) {
      const float4* xp = (const float4*)(xrow + (ks + 2) * 64);
#pragma unroll
      for (int j = 0; j < 4; ++j) xa[pfree][j] = xp[j];
    }
    bf16x8 bnxt[3][2];
    if (ks < 15) {
      const int k1 = (ks + 1) << 6;
#pragma unroll
      for (int nf = 0; nf < 3; ++nf)
#pragma unroll
        for (int kf = 0; kf < 2; ++kf)
          bnxt[nf][kf] = *(const bf16x8*)(wp[nf] + k1 + kf * 32);
    }

    bf16x8 afr[4][2];
#pragma unroll
    for (int mf = 0; mf < 4; ++mf)
#pragma unroll
      for (int kf = 0; kf < 2; ++kf)
        afr[mf][kf] = *(bf16x8*)lds_swz(xs[cur], mf * 16 + q16, kf * 32 + g * 8);

#pragma unroll
    for (int mf = 0; mf < 4; ++mf)
#pragma unroll
      for (int nf = 0; nf < 3; ++nf)
#pragma unroll
        for (int kf = 0; kf < 2; ++kf)
          acc[mf][nf] = __builtin_amdgcn_mfma_f32_16x16x32_bf16(
              afr[mf][kf], bcur[nf][kf], acc[mf][nf], 0, 0, 0);

    if (ks < 15) {
      bf16x8 s0, s1;
      pack16(xa[pnext][0], xa[pnext][1], xa[pnext][2], xa[pnext][3], s0, s1);
      *(bf16x8*)lds_swz(xs[cur ^ 1], srow, sc) = s0;
      *(bf16x8*)lds_swz(xs[cur ^ 1], srow, sc + 8) = s1;
      __syncthreads();
      cur ^= 1;
#pragma unroll
      for (int nf = 0; nf < 3; ++nf)
#pragma unroll
        for (int kf = 0; kf < 2; ++kf) bcur[nf][kf] = bnxt[nf][kf];
    }
  }

#pragma unroll
  for (int nf = 0; nf < 3; ++nf) {
    const int n = w * 48 + nf * 16 + q16;
    const int mat = n >> 6;  // frag-uniform
    const int h = n & 63;
    if (mat < 2) {
      short* outp = mat ? ko : qo;
      const float fac = mat ? 1.0f : QK_SCALE;
#pragma unroll
      for (int mf = 0; mf < 4; ++mf)
#pragma unroll
        for (int r = 0; r < 4; ++r)
          outp[(r0 + mf * 16 + g * 4 + r) * HH + h] = f2bf(acc[mf][nf][r] * fac);
    } else {
      const int bb = (int)(r0 >> 11);
      const int tloc = (int)(r0 & 2047);
#pragma unroll
      for (int mf = 0; mf < 4; ++mf) {
        bf16x4 pk;
#pragma unroll
        for (int r = 0; r < 4; ++r) pk[r] = f2bf(acc[mf][nf][r]);
        *(bf16x4*)&vt[((size_t)bb * HH + h) * TT + tloc + mf * 16 + g * 4] = pk;
      }
    }
  }
}

// ---------------------------------------------------------------------------
// Flash attention, bf16 MFMA, SWAPPED-QK + in-register P (no P LDS bounce).
// S^T = mfma(K,Q): lane (q16,g) holds sfr[nf][r] = S[key=16nf+4g+r][q=q16].
// Row-max: 16 per-lane fmax + 2 shfl_xor (g-groups 16/32) -> m is g-uniform
// per q (fixes round-7 NaN: all-masked lane subsets gave -inf - -inf).
// PV 16x16x32 with key<->k-slot bijection key = 32m + 16*(j>>2) + 4g + (j&3):
// S^T C-chunks ARE the A-frag; B-frags are two ds_read_b64 from V^T.
// KVBLK=64, double-buffered (32 KB LDS), 1 barrier/chunk, 4 blocks/CU.
// ---------------------------------------------------------------------------
__global__ __launch_bounds__(256, 4) void attn_mfma(
    const short* __restrict__ q, const short* __restrict__ k,
    const short* __restrict__ vt, float* __restrict__ out) {
  __shared__ short klds[2][64 * 64];  // 16 KB, K [key][d] (buf0 also Q stage)
  __shared__ short vlds[2][64 * 64];  // 16 KB, V^T [h][key]

  const int bx = blockIdx.x;  // 0..31
  const int b = blockIdx.y;   // 0..15
  const int qt = (b >= 8) ? bx : (31 - bx);
  const int t0 = qt << 6;
  const int tid = threadIdx.x;
  const int lane = tid & 63;
  const int w = tid >> 6;  // 0..3, wave owns q rows t0+w*16..+15
  const int q16 = lane & 15;
  const int g = lane >> 4;
  const int NC = qt + 1;  // 64-key chunks

  const size_t brow = (size_t)b * TT;
  const short* kg = k + brow * HH;
  const short* vtg = vt + (size_t)b * HH * TT;

  const int srow = tid >> 2;        // 0..63
  const int scol = (tid & 3) << 4;  // 0,16,32,48

  // issue chunk-0 K/V loads first (hide under Q staging)
  bf16x8 kr0 = *(const bf16x8*)&kg[srow * HH + scol];
  bf16x8 kr1 = *(const bf16x8*)&kg[srow * HH + scol + 8];
  bf16x8 vr0 = *(const bf16x8*)&vtg[srow * TT + scol];
  bf16x8 vr1 = *(const bf16x8*)&vtg[srow * TT + scol + 8];

  // stage Q tile into klds[0], pull per-wave Q frags (B-operand layout)
  {
    const short* qsrc = q + (brow + t0 + srow) * HH;
    *(bf16x8*)lds_swz(klds[0], srow, scol) = *(const bf16x8*)&qsrc[scol];
    *(bf16x8*)lds_swz(klds[0], srow, scol + 8) = *(const bf16x8*)&qsrc[scol + 8];
  }
  __syncthreads();
  bf16x8 qa[2];
#pragma unroll
  for (int kf = 0; kf < 2; ++kf)
    qa[kf] = *(bf16x8*)lds_swz(klds[0], w * 16 + q16, kf * 32 + g * 8);
  __syncthreads();

  // write chunk 0
  *(bf16x8*)lds_swz(klds[0], srow, scol) = kr0;
  *(bf16x8*)lds_swz(klds[0], srow, scol + 8) = kr1;
  *(bf16x8*)lds_swz(vlds[0], srow, scol) = vr0;
  *(bf16x8*)lds_swz(vlds[0], srow, scol + 8) = vr1;
  __syncthreads();

  f32x4 po[4];  // O[q=4g+r][h=nf*16+q16]
  f32x4 lacc = (f32x4){0.f, 0.f, 0.f, 0.f};
  float m = -INFINITY;  // per-lane frame: q = q16 (S^T column), g-uniform
#pragma unroll
  for (int nf = 0; nf < 4; ++nf) po[nf] = (f32x4){0.f, 0.f, 0.f, 0.f};

  const bf16x8 ones = {0x3F80, 0x3F80, 0x3F80, 0x3F80,
                       0x3F80, 0x3F80, 0x3F80, 0x3F80};
  int cur = 0;

  for (int c = 0; c < NC; ++c) {
    const bool notlast = (c + 1 < NC);
    if (notlast) {  // T14: issue next chunk's globals before compute
      const int s1 = (c + 1) << 6;
      kr0 = *(const bf16x8*)&kg[(s1 + srow) * HH + scol];
      kr1 = *(const bf16x8*)&kg[(s1 + srow) * HH + scol + 8];
      vr0 = *(const bf16x8*)&vtg[srow * TT + s1 + scol];
      vr1 = *(const bf16x8*)&vtg[srow * TT + s1 + scol + 8];
    }

    // ---- S^T = K . Q^T (swapped operands; Q pre-scaled for exp2) ----
    f32x4 sfr[4];
#pragma unroll
    for (int nf = 0; nf < 4; ++nf) sfr[nf] = (f32x4){0.f, 0.f, 0.f, 0.f};
    __builtin_amdgcn_s_setprio(1);
#pragma unroll
    for (int nf = 0; nf < 4; ++nf)
#pragma unroll
      for (int kf = 0; kf < 2; ++kf) {
        bf16x8 kb = *(bf16x8*)lds_swz(klds[cur], nf * 16 + q16, kf * 32 + g * 8);
        sfr[nf] = __builtin_amdgcn_mfma_f32_16x16x32_bf16(kb, qa[kf], sfr[nf], 0, 0, 0);
      }
    __builtin_amdgcn_s_setprio(0);

    // ---- causal mask (diagonal chunk only): key 16nf+4g+r > w*16+q16 ----
    if (c == NC - 1) {
      const int qloc = w * 16 + q16;
#pragma unroll
      for (int nf = 0; nf < 4; ++nf)
#pragma unroll
        for (int r = 0; r < 4; ++r)
          if (16 * nf + 4 * g + r > qloc) sfr[nf][r] = -INFINITY;
    }

    // ---- row max: per-lane over its 16 keys, then across g-groups ----
    float pm;
    {
      f32x4 t01 = (f32x4){fmaxf(sfr[0][0], sfr[1][0]), fmaxf(sfr[0][1], sfr[1][1]),
                          fmaxf(sfr[0][2], sfr[1][2]), fmaxf(sfr[0][3], sfr[1][3])};
      f32x4 t23 = (f32x4){fmaxf(sfr[2][0], sfr[3][0]), fmaxf(sfr[2][1], sfr[3][1]),
                          fmaxf(sfr[2][2], sfr[3][2]), fmaxf(sfr[2][3], sfr[3][3])};
      pm = fmaxf(fmaxf(fmaxf(t01[0], t23[0]), fmaxf(t01[1], t23[1])),
                 fmaxf(fmaxf(t01[2], t23[2]), fmaxf(t01[3], t23[3])));
      // lanes sharing q16 but different g hold disjoint key subsets:
      pm = fmaxf(pm, __shfl_xor(pm, 16));
      pm = fmaxf(pm, __shfl_xor(pm, 32));
    }

    // ---- defer-max (T13, THR=8 in log2 units) ----
    if (__any(pm - m > 8.f)) {
      const float mn = fmaxf(m, pm);
      const float corr = exp2f(m - mn);  // 0 on first chunk
      m = mn;
      // corr is in q16-frame; po/lacc rows are q = 4g+r -> shfl bridge
      const int sbase = (lane & 48) + ((lane >> 4) << 2);
#pragma unroll
      for (int r = 0; r < 4; ++r) {
        const float cr = __shfl(corr, sbase + r);
        lacc[r] *= cr;
#pragma unroll
        for (int nf = 0; nf < 4; ++nf) po[nf][r] *= cr;
      }
    }

    // ---- P = exp2(S - m), straight to bf16 A-frags (no LDS) ----
    bf16x8 pa[2];
#pragma unroll
    for (int m2 = 0; m2 < 2; ++m2)
#pragma unroll
      for (int j = 0; j < 8; ++j)
        pa[m2][j] = f2bf_up(exp2f(sfr[2 * m2 + (j >> 2)][j & 3] - m));

    // ---- O += P.V ; l += P.1  (key map: 32m + 16*(j>>2) + 4g + (j&3)) ----
    __builtin_amdgcn_s_setprio(1);
#pragma unroll
    for (int m2 = 0; m2 < 2; ++m2) {
#pragma unroll
      for (int nf = 0; nf < 4; ++nf) {
        bf16x4 lo = *(bf16x4*)lds_swz(vlds[cur], nf * 16 + q16, 32 * m2 + 4 * g);
        bf16x4 hi = *(bf16x4*)lds_swz(vlds[cur], nf * 16 + q16, 32 * m2 + 16 + 4 * g);
        bf16x8 vb = __builtin_shufflevector(lo, hi, 0, 1, 2, 3, 4, 5, 6, 7);
        po[nf] = __builtin_amdgcn_mfma_f32_16x16x32_bf16(pa[m2], vb, po[nf], 0, 0, 0);
      }
      lacc = __builtin_amdgcn_mfma_f32_16x16x32_bf16(pa[m2], ones, lacc, 0, 0, 0);
    }
    __builtin_amdgcn_s_setprio(0);

    if (notlast) {
      *(bf16x8*)lds_swz(klds[cur ^ 1], srow, scol) = kr0;
      *(bf16x8*)lds_swz(klds[cur ^ 1], srow, scol + 8) = kr1;
      *(bf16x8*)lds_swz(vlds[cur ^ 1], srow, scol) = vr0;
      *(bf16x8*)lds_swz(vlds[cur ^ 1], srow, scol + 8) = vr1;
      __syncthreads();
      cur ^= 1;
    }
  }

  const int qrow = t0 + w * 16 + g * 4;
#pragma unroll
  for (int nf = 0; nf < 4; ++nf) {
    const int h = nf * 16 + q16;
#pragma unroll
    for (int r = 0; r < 4; ++r)
      out[(brow + qrow + r) * HH + h] = po[nf][r] / lacc[r];
  }
}

extern "C" void kernel_launch(void* const* d_in, const int* in_sizes, int n_in,
                              void* d_out, int out_size, void* d_ws, size_t ws_size,
                              hipStream_t stream) {
  const float* x  = (const float*)d_in[0];
  const float* Wq = (const float*)d_in[1];
  const float* Wk = (const float*)d_in[2];
  const float* Wv = (const float*)d_in[3];
  float* out = (float*)d_out;

  const size_t bth = (size_t)BB * TT * HH;  // 2,097,152
  short* qb  = (short*)d_ws;
  short* kb  = qb + bth;
  short* vtb = kb + bth;
  short* wtb = vtb + bth;  // 192*1024 bf16

  pack_wt<<<96, 256, 0, stream>>>(Wq, Wk, Wv, wtb);
  qkv_mfma<<<(BB * TT) / 64, 256, 0, stream>>>(x, wtb, qb, kb, vtb);
  attn_mfma<<<dim3(32, BB), 256, 0, stream>>>(qb, kb, vtb, out);
}

// Round 9
// 80.383 us; speedup vs baseline: 1.0803x; 1.0033x over previous
//
#include <hip/hip_runtime.h>
#include <math.h>

#define BB 16
#define TT 2048
#define DD 1024
#define HH 64
#define QK_SCALE 0.18033688011112042f  // 0.125 * log2(e)  (exp2-domain softmax)

typedef short bf16x8 __attribute__((ext_vector_type(8)));
typedef short bf16x4 __attribute__((ext_vector_type(4)));
typedef float f32x4 __attribute__((ext_vector_type(4)));

__device__ __forceinline__ short f2bf(float f) {  // RNE
  union { float f; unsigned u; } c; c.f = f;
  unsigned u = c.u + 0x7FFFu + ((c.u >> 16) & 1u);
  return (short)(u >> 16);
}
__device__ __forceinline__ short f2bf_up(float f) {  // round-half-up (P>=0)
  union { float f; unsigned u; } c; c.f = f;
  return (short)((c.u + 0x8000u) >> 16);
}

// 64-col bf16 tile (128B row stride): XOR-swizzle 16B units by row&7.
__device__ __forceinline__ void* lds_swz(void* base, int row, int col) {
  int byte = (row << 7) + (col << 1);
  byte ^= (row & 7) << 4;
  return (void*)((char*)base + byte);
}

__device__ __forceinline__ void pack16(const float4& a0, const float4& a1,
                                       const float4& a2, const float4& a3,
                                       bf16x8& s0, bf16x8& s1) {
  s0[0] = f2bf(a0.x); s0[1] = f2bf(a0.y); s0[2] = f2bf(a0.z); s0[3] = f2bf(a0.w);
  s0[4] = f2bf(a1.x); s0[5] = f2bf(a1.y); s0[6] = f2bf(a1.z); s0[7] = f2bf(a1.w);
  s1[0] = f2bf(a2.x); s1[1] = f2bf(a2.y); s1[2] = f2bf(a2.z); s1[3] = f2bf(a2.w);
  s1[4] = f2bf(a3.x); s1[5] = f2bf(a3.y); s1[6] = f2bf(a3.z); s1[7] = f2bf(a3.w);
}

// ---------------------------------------------------------------------------
// Pack Wq|Wk|Wv (fp32 [D][H]) -> Wt bf16 [192][1024]  (n-major, k contiguous)
// ---------------------------------------------------------------------------
__global__ __launch_bounds__(256) void pack_wt(
    const float* __restrict__ Wq, const float* __restrict__ Wk,
    const float* __restrict__ Wv, short* __restrict__ wt) {
  const int idx = blockIdx.x * 256 + threadIdx.x;
  const int n = idx >> 7;
  const int k0 = (idx & 127) << 3;
  const float* W = (n < 64) ? Wq : (n < 128) ? Wk : Wv;
  const int h = n & 63;
  bf16x8 o;
#pragma unroll
  for (int j = 0; j < 8; ++j) o[j] = f2bf(W[(k0 + j) * HH + h]);
  *(bf16x8*)&wt[n * DD + k0] = o;
}

// ---------------------------------------------------------------------------
// QKV GEMM, bf16 MFMA, depth-2 x prefetch. Q pre-scaled by QK_SCALE;
// V written transposed to vt [b][h][t].   (identical to round 8)
// ---------------------------------------------------------------------------
__global__ __launch_bounds__(256) void qkv_mfma(
    const float* __restrict__ x, const short* __restrict__ wt,
    short* __restrict__ qo, short* __restrict__ ko, short* __restrict__ vt) {
  __shared__ short xs[2][64 * 64];
  const int tid = threadIdx.x;
  const int lane = tid & 63;
  const int w = tid >> 6;
  const int q16 = lane & 15;
  const int g = lane >> 4;
  const size_t r0 = (size_t)blockIdx.x * 64;

  const int srow = tid >> 2;
  const int sc = (tid & 3) << 4;
  const float* xrow = x + (r0 + srow) * DD + sc;

  f32x4 acc[4][3];
#pragma unroll
  for (int mf = 0; mf < 4; ++mf)
#pragma unroll
    for (int nf = 0; nf < 3; ++nf) acc[mf][nf] = (f32x4){0.f, 0.f, 0.f, 0.f};

  const short* wp[3];
#pragma unroll
  for (int nf = 0; nf < 3; ++nf)
    wp[nf] = wt + (size_t)(w * 48 + nf * 16 + q16) * DD + g * 8;

  float4 xa[2][4];  // two in-flight x reg-sets (unroll-2 keeps idx static)
  {
    const float4* xp = (const float4*)xrow;
#pragma unroll
    for (int j = 0; j < 4; ++j) xa[0][j] = xp[j];
    bf16x8 s0, s1;
    pack16(xa[0][0], xa[0][1], xa[0][2], xa[0][3], s0, s1);
    *(bf16x8*)lds_swz(xs[0], srow, sc) = s0;
    *(bf16x8*)lds_swz(xs[0], srow, sc + 8) = s1;
    const float4* xp1 = (const float4*)(xrow + 64);
#pragma unroll
    for (int j = 0; j < 4; ++j) xa[1][j] = xp1[j];
  }
  bf16x8 bcur[3][2];
#pragma unroll
  for (int nf = 0; nf < 3; ++nf)
#pragma unroll
    for (int kf = 0; kf < 2; ++kf)
      bcur[nf][kf] = *(const bf16x8*)(wp[nf] + kf * 32);
  __syncthreads();

  int cur = 0;
#pragma unroll 2
  for (int ks = 0; ks < 16; ++ks) {
    const int pnext = (ks + 1) & 1;  // set holding x(ks+1)
    const int pfree = ks & 1;        // set to refill with x(ks+2)
    if (ks < 14) {
      const float4* xp = (const float4*)(xrow + (ks + 2) * 64);
#pragma unroll
      for (int j = 0; j < 4; ++j) xa[pfree][j] = xp[j];
    }
    bf16x8 bnxt[3][2];
    if (ks < 15) {
      const int k1 = (ks + 1) << 6;
#pragma unroll
      for (int nf = 0; nf < 3; ++nf)
#pragma unroll
        for (int kf = 0; kf < 2; ++kf)
          bnxt[nf][kf] = *(const bf16x8*)(wp[nf] + k1 + kf * 32);
    }

    bf16x8 afr[4][2];
#pragma unroll
    for (int mf = 0; mf < 4; ++mf)
#pragma unroll
      for (int kf = 0; kf < 2; ++kf)
        afr[mf][kf] = *(bf16x8*)lds_swz(xs[cur], mf * 16 + q16, kf * 32 + g * 8);

#pragma unroll
    for (int mf = 0; mf < 4; ++mf)
#pragma unroll
      for (int nf = 0; nf < 3; ++nf)
#pragma unroll
        for (int kf = 0; kf < 2; ++kf)
          acc[mf][nf] = __builtin_amdgcn_mfma_f32_16x16x32_bf16(
              afr[mf][kf], bcur[nf][kf], acc[mf][nf], 0, 0, 0);

    if (ks < 15) {
      bf16x8 s0, s1;
      pack16(xa[pnext][0], xa[pnext][1], xa[pnext][2], xa[pnext][3], s0, s1);
      *(bf16x8*)lds_swz(xs[cur ^ 1], srow, sc) = s0;
      *(bf16x8*)lds_swz(xs[cur ^ 1], srow, sc + 8) = s1;
      __syncthreads();
      cur ^= 1;
#pragma unroll
      for (int nf = 0; nf < 3; ++nf)
#pragma unroll
        for (int kf = 0; kf < 2; ++kf) bcur[nf][kf] = bnxt[nf][kf];
    }
  }

#pragma unroll
  for (int nf = 0; nf < 3; ++nf) {
    const int n = w * 48 + nf * 16 + q16;
    const int mat = n >> 6;  // frag-uniform
    const int h = n & 63;
    if (mat < 2) {
      short* outp = mat ? ko : qo;
      const float fac = mat ? 1.0f : QK_SCALE;
#pragma unroll
      for (int mf = 0; mf < 4; ++mf)
#pragma unroll
        for (int r = 0; r < 4; ++r)
          outp[(r0 + mf * 16 + g * 4 + r) * HH + h] = f2bf(acc[mf][nf][r] * fac);
    } else {
      const int bb = (int)(r0 >> 11);
      const int tloc = (int)(r0 & 2047);
#pragma unroll
      for (int mf = 0; mf < 4; ++mf) {
        bf16x4 pk;
#pragma unroll
        for (int r = 0; r < 4; ++r) pk[r] = f2bf(acc[mf][nf][r]);
        *(bf16x4*)&vt[((size_t)bb * HH + h) * TT + tloc + mf * 16 + g * 4] = pk;
      }
    }
  }
}

// ---------------------------------------------------------------------------
// Flash attention, bf16 MFMA, swapped-QK + in-register P.
// NEW vs round 8:
//  (1) 1D grid (512) with XCD swizzle: b=(id&7)|((id>>3)&1)<<3, kk=id>>4,
//      qt = kk<16 ? 31-kk : kk-16  -> each XCD touches 2 batches (K/V 1 MB,
//      L2-resident) and heavy tiles dispatch first.
//  (2) V^T staged with key->slot permutation slot=(k&3)|((k>>4)&1)<<2|
//      ((k>>2)&3)<<3|(k&32) so each PV B-frag is ONE ds_read_b128
//      (PV LDS reads halve). Element order matches pa k-slot bijection.
// ---------------------------------------------------------------------------
__global__ __launch_bounds__(256, 4) void attn_mfma(
    const short* __restrict__ q, const short* __restrict__ k,
    const short* __restrict__ vt, float* __restrict__ out) {
  __shared__ short klds[2][64 * 64];  // 16 KB, K [key][d] (buf0 also Q stage)
  __shared__ short vlds[2][64 * 64];  // 16 KB, V^T [h][slot] permuted

  const int id = blockIdx.x;  // 0..511
  const int b = (id & 7) | (((id >> 3) & 1) << 3);
  const int kk = id >> 4;     // 0..31
  const int qt = (kk < 16) ? (31 - kk) : (kk - 16);
  const int t0 = qt << 6;
  const int tid = threadIdx.x;
  const int lane = tid & 63;
  const int w = tid >> 6;  // 0..3, wave owns q rows t0+w*16..+15
  const int q16 = lane & 15;
  const int g = lane >> 4;
  const int NC = qt + 1;  // 64-key chunks

  const size_t brow = (size_t)b * TT;
  const short* kg = k + brow * HH;
  const short* vtg = vt + (size_t)b * HH * TT;

  const int srow = tid >> 2;        // 0..63
  const int scol = (tid & 3) << 4;  // 0,16,32,48 (elements / slots)

  // V permuted staging constants: groups A (slots scol..+7), B (scol+8..+15)
  const int vgA = (scol >> 3) & 3;   // g-bits of group A
  const int vgB = ((scol + 8) >> 3) & 3;
  const int vm2 = scol >> 5;         // m2 bit
  const short* vrow_p = vtg + srow * TT + vm2 * 32;

  // issue chunk-0 K/V loads first (hide under Q staging)
  bf16x8 kr0 = *(const bf16x8*)&kg[srow * HH + scol];
  bf16x8 kr1 = *(const bf16x8*)&kg[srow * HH + scol + 8];
  bf16x4 va0 = *(const bf16x4*)(vrow_p + 4 * vgA);
  bf16x4 va1 = *(const bf16x4*)(vrow_p + 16 + 4 * vgA);
  bf16x4 vb0 = *(const bf16x4*)(vrow_p + 4 * vgB);
  bf16x4 vb1 = *(const bf16x4*)(vrow_p + 16 + 4 * vgB);

  // stage Q tile into klds[0], pull per-wave Q frags (B-operand layout)
  {
    const short* qsrc = q + (brow + t0 + srow) * HH;
    *(bf16x8*)lds_swz(klds[0], srow, scol) = *(const bf16x8*)&qsrc[scol];
    *(bf16x8*)lds_swz(klds[0], srow, scol + 8) = *(const bf16x8*)&qsrc[scol + 8];
  }
  __syncthreads();
  bf16x8 qa[2];
#pragma unroll
  for (int kf = 0; kf < 2; ++kf)
    qa[kf] = *(bf16x8*)lds_swz(klds[0], w * 16 + q16, kf * 32 + g * 8);
  __syncthreads();

  // write chunk 0
  *(bf16x8*)lds_swz(klds[0], srow, scol) = kr0;
  *(bf16x8*)lds_swz(klds[0], srow, scol + 8) = kr1;
  *(bf16x8*)lds_swz(vlds[0], srow, scol) =
      __builtin_shufflevector(va0, va1, 0, 1, 2, 3, 4, 5, 6, 7);
  *(bf16x8*)lds_swz(vlds[0], srow, scol + 8) =
      __builtin_shufflevector(vb0, vb1, 0, 1, 2, 3, 4, 5, 6, 7);
  __syncthreads();

  f32x4 po[4];  // O[q=4g+r][h=nf*16+q16]
  f32x4 lacc = (f32x4){0.f, 0.f, 0.f, 0.f};
  float m = -INFINITY;  // per-lane frame: q = q16 (S^T column), g-uniform
#pragma unroll
  for (int nf = 0; nf < 4; ++nf) po[nf] = (f32x4){0.f, 0.f, 0.f, 0.f};

  const bf16x8 ones = {0x3F80, 0x3F80, 0x3F80, 0x3F80,
                       0x3F80, 0x3F80, 0x3F80, 0x3F80};
  int cur = 0;

  for (int c = 0; c < NC; ++c) {
    const bool notlast = (c + 1 < NC);
    if (notlast) {  // T14: issue next chunk's globals before compute
      const int s1 = (c + 1) << 6;
      kr0 = *(const bf16x8*)&kg[(s1 + srow) * HH + scol];
      kr1 = *(const bf16x8*)&kg[(s1 + srow) * HH + scol + 8];
      va0 = *(const bf16x4*)(vrow_p + s1 + 4 * vgA);
      va1 = *(const bf16x4*)(vrow_p + s1 + 16 + 4 * vgA);
      vb0 = *(const bf16x4*)(vrow_p + s1 + 4 * vgB);
      vb1 = *(const bf16x4*)(vrow_p + s1 + 16 + 4 * vgB);
    }

    // ---- S^T = K . Q^T (swapped operands; Q pre-scaled for exp2) ----
    f32x4 sfr[4];
#pragma unroll
    for (int nf = 0; nf < 4; ++nf) sfr[nf] = (f32x4){0.f, 0.f, 0.f, 0.f};
    __builtin_amdgcn_s_setprio(1);
#pragma unroll
    for (int nf = 0; nf < 4; ++nf)
#pragma unroll
      for (int kf = 0; kf < 2; ++kf) {
        bf16x8 kb = *(bf16x8*)lds_swz(klds[cur], nf * 16 + q16, kf * 32 + g * 8);
        sfr[nf] = __builtin_amdgcn_mfma_f32_16x16x32_bf16(kb, qa[kf], sfr[nf], 0, 0, 0);
      }
    __builtin_amdgcn_s_setprio(0);

    // ---- causal mask (diagonal chunk only): key 16nf+4g+r > w*16+q16 ----
    if (c == NC - 1) {
      const int qloc = w * 16 + q16;
#pragma unroll
      for (int nf = 0; nf < 4; ++nf)
#pragma unroll
        for (int r = 0; r < 4; ++r)
          if (16 * nf + 4 * g + r > qloc) sfr[nf][r] = -INFINITY;
    }

    // ---- row max: per-lane over its 16 keys, then across g-groups ----
    float pm;
    {
      f32x4 t01 = (f32x4){fmaxf(sfr[0][0], sfr[1][0]), fmaxf(sfr[0][1], sfr[1][1]),
                          fmaxf(sfr[0][2], sfr[1][2]), fmaxf(sfr[0][3], sfr[1][3])};
      f32x4 t23 = (f32x4){fmaxf(sfr[2][0], sfr[3][0]), fmaxf(sfr[2][1], sfr[3][1]),
                          fmaxf(sfr[2][2], sfr[3][2]), fmaxf(sfr[2][3], sfr[3][3])};
      pm = fmaxf(fmaxf(fmaxf(t01[0], t23[0]), fmaxf(t01[1], t23[1])),
                 fmaxf(fmaxf(t01[2], t23[2]), fmaxf(t01[3], t23[3])));
      pm = fmaxf(pm, __shfl_xor(pm, 16));
      pm = fmaxf(pm, __shfl_xor(pm, 32));
    }

    // ---- defer-max (T13, THR=8 in log2 units) ----
    if (__any(pm - m > 8.f)) {
      const float mn = fmaxf(m, pm);
      const float corr = exp2f(m - mn);  // 0 on first chunk
      m = mn;
      const int sbase = (lane & 48) + ((lane >> 4) << 2);
#pragma unroll
      for (int r = 0; r < 4; ++r) {
        const float cr = __shfl(corr, sbase + r);
        lacc[r] *= cr;
#pragma unroll
        for (int nf = 0; nf < 4; ++nf) po[nf][r] *= cr;
      }
    }

    // ---- P = exp2(S - m), straight to bf16 A-frags (no LDS) ----
    bf16x8 pa[2];
#pragma unroll
    for (int m2 = 0; m2 < 2; ++m2)
#pragma unroll
      for (int j = 0; j < 8; ++j)
        pa[m2][j] = f2bf_up(exp2f(sfr[2 * m2 + (j >> 2)][j & 3] - m));

    // ---- O += P.V ; l += P.1  (permuted V: one b128 per B-frag) ----
    __builtin_amdgcn_s_setprio(1);
#pragma unroll
    for (int m2 = 0; m2 < 2; ++m2) {
#pragma unroll
      for (int nf = 0; nf < 4; ++nf) {
        bf16x8 vb = *(bf16x8*)lds_swz(vlds[cur], nf * 16 + q16, m2 * 32 + g * 8);
        po[nf] = __builtin_amdgcn_mfma_f32_16x16x32_bf16(pa[m2], vb, po[nf], 0, 0, 0);
      }
      lacc = __builtin_amdgcn_mfma_f32_16x16x32_bf16(pa[m2], ones, lacc, 0, 0, 0);
    }
    __builtin_amdgcn_s_setprio(0);

    if (notlast) {
      *(bf16x8*)lds_swz(klds[cur ^ 1], srow, scol) = kr0;
      *(bf16x8*)lds_swz(klds[cur ^ 1], srow, scol + 8) = kr1;
      *(bf16x8*)lds_swz(vlds[cur ^ 1], srow, scol) =
          __builtin_shufflevector(va0, va1, 0, 1, 2, 3, 4, 5, 6, 7);
      *(bf16x8*)lds_swz(vlds[cur ^ 1], srow, scol + 8) =
          __builtin_shufflevector(vb0, vb1, 0, 1, 2, 3, 4, 5, 6, 7);
      __syncthreads();
      cur ^= 1;
    }
  }

  const int qrow = t0 + w * 16 + g * 4;
#pragma unroll
  for (int nf = 0; nf < 4; ++nf) {
    const int h = nf * 16 + q16;
#pragma unroll
    for (int r = 0; r < 4; ++r)
      out[(brow + qrow + r) * HH + h] = po[nf][r] / lacc[r];
  }
}

extern "C" void kernel_launch(void* const* d_in, const int* in_sizes, int n_in,
                              void* d_out, int out_size, void* d_ws, size_t ws_size,
                              hipStream_t stream) {
  const float* x  = (const float*)d_in[0];
  const float* Wq = (const float*)d_in[1];
  const float* Wk = (const float*)d_in[2];
  const float* Wv = (const float*)d_in[3];
  float* out = (float*)d_out;

  const size_t bth = (size_t)BB * TT * HH;  // 2,097,152
  short* qb  = (short*)d_ws;
  short* kb  = qb + bth;
  short* vtb = kb + bth;
  short* wtb = vtb + bth;  // 192*1024 bf16

  pack_wt<<<96, 256, 0, stream>>>(Wq, Wk, Wv, wtb);
  qkv_mfma<<<(BB * TT) / 64, 256, 0, stream>>>(x, wtb, qb, kb, vtb);
  attn_mfma<<<512, 256, 0, stream>>>(qb, kb, vtb, out);
}